// Round 7
// baseline (5530.623 us; speedup 1.0000x reference)
//
#include <hip/hip_runtime.h>
#include <math.h>

#define T_ 200
#define WROW 284                       // LDS row stride (256 + swizzle room)
#define SMEM_FLOATS (128 * WROW + 16 * WROW)
#define SMEM_BYTES (SMEM_FLOATS * 4)   // 163,584 <= 163,840 (160 KiB)

__device__ __forceinline__ float fsig(float x) {
  return 1.f / (1.f + __expf(-x));
}
__device__ __forceinline__ float ftanh(float x) {
  return 1.f - 2.f / (__expf(2.f * x) + 1.f);   // exact at +-inf, no NaN
}

// ---------------- xg GEMM with fused embedding gather + masked-tile early exit
__global__ __launch_bounds__(256) void xg_gemm(
    const int* __restrict__ bin, const int* __restrict__ bfe,
    const int* __restrict__ blen,
    const float* __restrict__ ctab, const float* __restrict__ ftab,
    const float* __restrict__ wih, const float* __restrict__ bias,
    float* __restrict__ xgslot, int t0, int sgn) {
  const int m0 = blockIdx.x * 64;
  const int rloc = m0 >> 8;
  const int t_blk = t0 + sgn * rloc;
  if (t_blk >= blen[m0 & 255]) return;   // fully masked tile

  __shared__ float As[32][68];
  __shared__ float Bs[32][132];
  const int tid = threadIdx.x;
  const int n0 = blockIdx.y * 128;

  const int mm = tid & 15;
  const int nn = tid >> 4;

  float acc[2][4][4];
  #pragma unroll
  for (int q = 0; q < 2; ++q)
    #pragma unroll
    for (int i = 0; i < 4; ++i)
      #pragma unroll
      for (int j2 = 0; j2 < 4; ++j2) acc[q][i][j2] = 0.f;

  const int ra = tid & 63, ka = tid >> 6;
  const int rb = tid & 127, kb = tid >> 7;

  const int bcol = (m0 + ra) & 255;
  const float* cr = ctab + ((size_t)bin[bcol * T_ + t_blk] << 8);
  const float* fr = ftab + ((size_t)bfe[bcol * T_ + t_blk] << 8);

  for (int ks = 0; ks < 256; ks += 32) {
    {
      const float* c0p = cr + ks + ka * 8;
      const float* f0p = fr + ks + ka * 8;
      float4 c0 = *(const float4*)(c0p);
      float4 c1 = *(const float4*)(c0p + 4);
      float4 f0 = *(const float4*)(f0p);
      float4 f1 = *(const float4*)(f0p + 4);
      int kk = ka * 8;
      As[kk + 0][ra] = c0.x * f0.x; As[kk + 1][ra] = c0.y * f0.y;
      As[kk + 2][ra] = c0.z * f0.z; As[kk + 3][ra] = c0.w * f0.w;
      As[kk + 4][ra] = c1.x * f1.x; As[kk + 5][ra] = c1.y * f1.y;
      As[kk + 6][ra] = c1.z * f1.z; As[kk + 7][ra] = c1.w * f1.w;
    }
    {
      const float* src = wih + (size_t)(n0 + rb) * 256 + ks + kb * 16;
      float4 v0 = *(const float4*)(src);
      float4 v1 = *(const float4*)(src + 4);
      float4 v2 = *(const float4*)(src + 8);
      float4 v3 = *(const float4*)(src + 12);
      int kk = kb * 16;
      Bs[kk + 0][rb] = v0.x; Bs[kk + 1][rb] = v0.y; Bs[kk + 2][rb] = v0.z; Bs[kk + 3][rb] = v0.w;
      Bs[kk + 4][rb] = v1.x; Bs[kk + 5][rb] = v1.y; Bs[kk + 6][rb] = v1.z; Bs[kk + 7][rb] = v1.w;
      Bs[kk + 8][rb] = v2.x; Bs[kk + 9][rb] = v2.y; Bs[kk +10][rb] = v2.z; Bs[kk +11][rb] = v2.w;
      Bs[kk +12][rb] = v3.x; Bs[kk +13][rb] = v3.y; Bs[kk +14][rb] = v3.z; Bs[kk +15][rb] = v3.w;
    }
    __syncthreads();
    for (int k = 0; k < 32; ++k) {
      float4 av = *(const float4*)&As[k][mm * 4];
      float4 b0 = *(const float4*)&Bs[k][nn * 4];
      float4 b1 = *(const float4*)&Bs[k][64 + nn * 4];
      float am[4] = {av.x, av.y, av.z, av.w};
      float bv[2][4] = {{b0.x, b0.y, b0.z, b0.w}, {b1.x, b1.y, b1.z, b1.w}};
      #pragma unroll
      for (int i = 0; i < 4; ++i)
        #pragma unroll
        for (int q = 0; q < 2; ++q)
          #pragma unroll
          for (int j2 = 0; j2 < 4; ++j2)
            acc[q][i][j2] += am[i] * bv[q][j2];
    }
    __syncthreads();
  }
  #pragma unroll
  for (int q = 0; q < 2; ++q) {
    int nc = n0 + q * 64 + nn * 4;
    float4 bv = *(const float4*)(bias + nc);
    #pragma unroll
    for (int i = 0; i < 4; ++i) {
      int row = m0 + mm * 4 + i;
      float4 o;
      o.x = acc[q][i][0] + bv.x;
      o.y = acc[q][i][1] + bv.y;
      o.z = acc[q][i][2] + bv.z;
      o.w = acc[q][i][3] + bv.w;
      *(float4*)(xgslot + (size_t)row * 1024 + nc) = o;
    }
  }
}

// ---------------- persistent LSTM chunk v5: ks16 tile (524 KB LDS/step) +
// flag barrier + dwordx4 agent staging.
// grid (16 bc, 8 js, 2 dir) = 256 blocks x 512 thr, 1 block/CU.
// Thread (ks=tid&15 k-slice of 16, bg=(tid>>4)&1 batch-half, rg=tid>>5):
// tile 8 rows x 8 batches x 16 k; acc[8][8]=64 regs (r5-proven no-spill).
// Butterfly: xor1/2/4 route 8 batches (batch = ks&7), xor8 pure k-reduce,
// u = ks>>3 picks j within the thread's row pair.
__global__ __launch_bounds__(512, 1) void lstm_chunk(
    const float* __restrict__ xgf, const float* __restrict__ xgb,
    const float* __restrict__ whf, const float* __restrict__ whb,
    const int* __restrict__ blen,
    float* __restrict__ hst, float* __restrict__ cst,
    float* __restrict__ hout, unsigned* __restrict__ bar,
    int s0, int nsteps) {
  extern __shared__ float smem[];
  float* wlds = smem;                 // [128][WROW]
  float* hlds = smem + 128 * WROW;    // [16][WROW]

  const int bc = blockIdx.x, js = blockIdx.y, dir = blockIdx.z;
  const int tid = threadIdx.x;
  const int ks = tid & 15;
  const int bg = (tid >> 4) & 1;
  const int rg = tid >> 5;            // 0..15
  const int grp = dir * 16 + bc;
  const float* wh = dir ? whb : whf;
  const float* xgp = dir ? xgb : xgf;

  // ---- stage W once per chunk (permuted rows: prow = rgs*8 + g*2 + u)
  #pragma unroll
  for (int i = 0; i < 16; ++i) {
    int f = tid + i * 512;            // float4 id 0..8191
    int prow = f >> 6;
    int k = (f & 63) << 2;
    int g = (prow >> 1) & 3, u = prow & 1, rgs = prow >> 3;
    int jg = js * 32 + rgs * 2 + u;
    float4 v = *(const float4*)(wh + ((size_t)(g * 256 + jg)) * 256 + k);
    *(float4*)&wlds[prow * WROW + k + ((k >> 5) << 2)] = v;
  }

  const int bl_th = bg * 8 + (ks & 7);      // local batch 0..15
  const int b_th = bc * 16 + bl_th;
  const int u_th = ks >> 3;
  const int jth = js * 32 + rg * 2 + u_th;
  const int cjth = jth + ((jth >> 5) << 2);
  const int len_th = blen[b_th];
  float c0 = cst[((size_t)dir * 256 + b_th) * 256 + jth];

  __syncthreads();   // W staged

  for (int r = 0; r < nsteps; ++r) {
    const int s = s0 + r;
    const int tt = dir ? (199 - s) : s;
    const int rslot = s & 1, wslot = 1 - rslot;

    // ---- xq loads first (latency hidden under staging + GEMM)
    float xq[4];
    #pragma unroll
    for (int g = 0; g < 4; ++g)
      xq[g] = xgp[((size_t)r * 256 + b_th) * 1024 + g * 256 + jth];

    // ---- stage h[16 b][256 k]: 2 agent-scope dwordx4 per thread
    const float* hsrc = hst + (((size_t)(rslot * 2 + dir)) * 256 + bc * 16) * 256;
    {
      const int f0 = tid, f1 = tid + 512;
      const int b0i = f0 >> 6, k0 = (f0 & 63) << 2;
      const int b1i = f1 >> 6, k1 = (f1 & 63) << 2;
      const float* p0 = hsrc + (b0i << 8) + k0;
      const float* p1 = hsrc + (b1i << 8) + k1;
      float4 v0, v1;
      asm volatile(
          "global_load_dwordx4 %0, %2, off sc0 sc1\n\t"
          "global_load_dwordx4 %1, %3, off sc0 sc1\n\t"
          "s_waitcnt vmcnt(0)"
          : "=&v"(v0), "=&v"(v1)
          : "v"(p0), "v"(p1)
          : "memory");
      *(float4*)&hlds[b0i * WROW + k0 + ((k0 >> 5) << 2)] = v0;
      *(float4*)&hlds[b1i * WROW + k1 + ((k1 >> 5) << 2)] = v1;
    }
    __syncthreads();

    // ---- GEMM: acc[i][bb] over this thread's 16-k slice
    float acc[8][8];
    #pragma unroll
    for (int i = 0; i < 8; ++i)
      #pragma unroll
      for (int bb = 0; bb < 8; ++bb) acc[i][bb] = 0.f;

    #pragma unroll
    for (int kq = 0; kq < 4; ++kq) {
      const int k = ks * 16 + kq * 4;
      const int col = k + ((k >> 5) << 2);
      float4 h4[8];
      #pragma unroll
      for (int bb = 0; bb < 8; ++bb)
        h4[bb] = *(const float4*)&hlds[(bg * 8 + bb) * WROW + col];
      #pragma unroll
      for (int i = 0; i < 8; ++i) {
        float4 w4 = *(const float4*)&wlds[(rg * 8 + i) * WROW + col];
        #pragma unroll
        for (int bb = 0; bb < 8; ++bb)
          acc[i][bb] += w4.x * h4[bb].x + w4.y * h4[bb].y +
                        w4.z * h4[bb].z + w4.w * h4[bb].w;
      }
    }

    // ---- butterfly: xor1/2/4 route 8 batches, xor8 pure k-reduce
    const int bit0 = ks & 1, bit1 = (ks >> 1) & 1, bit2 = (ks >> 2) & 1;
    float fin[8];
    #pragma unroll
    for (int i = 0; i < 8; ++i) {
      float a0 = bit0 ? acc[i][1] : acc[i][0];
      float s0v = bit0 ? acc[i][0] : acc[i][1];
      float a1 = bit0 ? acc[i][3] : acc[i][2];
      float s1v = bit0 ? acc[i][2] : acc[i][3];
      float a2 = bit0 ? acc[i][5] : acc[i][4];
      float s2v = bit0 ? acc[i][4] : acc[i][5];
      float a3 = bit0 ? acc[i][7] : acc[i][6];
      float s3v = bit0 ? acc[i][6] : acc[i][7];
      float r0 = a0 + __shfl_xor(s0v, 1);
      float r1 = a1 + __shfl_xor(s1v, 1);
      float r2 = a2 + __shfl_xor(s2v, 1);
      float r3 = a3 + __shfl_xor(s3v, 1);
      float b0v = bit1 ? r1 : r0;
      float t0v = bit1 ? r0 : r1;
      float b1v = bit1 ? r3 : r2;
      float t1v = bit1 ? r2 : r3;
      float q0 = b0v + __shfl_xor(t0v, 2);
      float q1 = b1v + __shfl_xor(t1v, 2);
      float d0 = bit2 ? q1 : q0;
      float e0 = bit2 ? q0 : q1;
      float z = d0 + __shfl_xor(e0, 4);
      fin[i] = z + __shfl_xor(z, 8);
    }

    // ---- cell update (1 cell per thread: batch b_th, hidden jth)
    float gi = fsig(fin[0 + u_th] + xq[0]);
    float gf = fsig(fin[2 + u_th] + xq[1]);
    float gg = ftanh(fin[4 + u_th] + xq[2]);
    float go = fsig(fin[6 + u_th] + xq[3]);
    float cn = gf * c0 + gi * gg;
    float hn = go * ftanh(cn);
    const bool mk = tt < len_th;
    if (mk) c0 = cn;
    float hold = hlds[bl_th * WROW + cjth];
    float hsv = mk ? hn : hold;
    __hip_atomic_store(
        hst + (((size_t)(wslot * 2 + dir)) * 256 + b_th) * 256 + jth,
        hsv, __ATOMIC_RELAXED, __HIP_MEMORY_SCOPE_AGENT);

    // ---- drain h stores, signal own flag, hout store overlaps the poll
    asm volatile("s_waitcnt vmcnt(0)" ::: "memory");
    __syncthreads();
    if (tid == 0)
      __hip_atomic_store(&bar[grp * 16 + js], (unsigned)(s + 1),
                         __ATOMIC_RELAXED, __HIP_MEMORY_SCOPE_AGENT);
    hout[(((size_t)dir * 200 + tt) * 256 + b_th) * 256 + jth] = mk ? hn : 0.f;
    // 8-lane parallel flag poll (no RMW serialization)
    if (tid < 64) {
      const unsigned tgt = (unsigned)(s + 1);
      bool done;
      do {
        unsigned v = tgt;
        if (tid < 8)
          v = __hip_atomic_load(&bar[grp * 16 + tid], __ATOMIC_RELAXED,
                                __HIP_MEMORY_SCOPE_AGENT);
        done = __all(v >= tgt);
      } while (!done);
    }
    __syncthreads();
  }

  cst[((size_t)dir * 256 + b_th) * 256 + jth] = c0;
}

// ---------------- feats[b][t][k] = [hf|hb] . W_tag[k] + b_tag[k]  (r2, proven)
__global__ __launch_bounds__(256) void feats_kernel(
    const float* __restrict__ h_out, const float* __restrict__ wtag,
    const float* __restrict__ btag, float* __restrict__ feats) {
  __shared__ float hcat[32][512];
  const int t = blockIdx.x, bc = blockIdx.y;
  const int tid = threadIdx.x;
  const float* hf = h_out + (((size_t)0 * 200 + t) * 256 + bc * 32) * 256;
  const float* hb = h_out + (((size_t)1 * 200 + t) * 256 + bc * 32) * 256;
  for (int i = tid; i < 2048; i += 256) {
    int row = i >> 6, c4 = (i & 63) << 2;
    *(float4*)&hcat[row][c4] = *(const float4*)(hf + (size_t)row * 256 + c4);
    *(float4*)&hcat[row][256 + c4] = *(const float4*)(hb + (size_t)row * 256 + c4);
  }
  __syncthreads();
  const int kk = tid & 63;
  const int bg = tid >> 6;
  if (kk < 52) {
    float acc[8];
    #pragma unroll
    for (int i = 0; i < 8; ++i) acc[i] = 0.f;
    const float* wr = wtag + (size_t)kk * 512;
    for (int jq = 0; jq < 128; ++jq) {
      float4 wv = *(const float4*)(wr + jq * 4);
      #pragma unroll
      for (int bi = 0; bi < 8; ++bi) {
        float4 hv = *(const float4*)&hcat[bg * 8 + bi][jq * 4];
        acc[bi] += wv.x * hv.x + wv.y * hv.y + wv.z * hv.z + wv.w * hv.w;
      }
    }
    float bv = btag[kk];
    #pragma unroll
    for (int bi = 0; bi < 8; ++bi)
      feats[(size_t)(bc * 32 + bg * 8 + bi) * 10400 + t * 52 + kk] = acc[bi] + bv;
  }
}

// ---------------- Viterbi v3: one WAVE per batch row (256 blocks x 64 thr).
// part broadcast via ds_read_b128 into regs; trans column + feats row staged;
// max over j = 4 independent 13-chains (ILP), combined in index order
// (preserves np first-index tie-break). Zero barriers in the t-loop.
__global__ __launch_bounds__(64) void viterbi_kernel(
    const float* __restrict__ feats, const float* __restrict__ trans,
    const int* __restrict__ blen, float* __restrict__ out) {
  __shared__ float flds[10400];
  __shared__ float pl[56];
  __shared__ unsigned char bp[199 * 52];

  const int b = blockIdx.x;
  const int lane = threadIdx.x;
  const int kk = (lane < 52) ? lane : 0;
  const float* fb = feats + (size_t)b * 10400;
  const int len = blen[b];

  // stage feats row (2600 float4, coalesced)
  for (int i = lane; i < 2600; i += 64)
    *(float4*)&flds[i * 4] = *(const float4*)(fb + i * 4);

  // trans column for this k (loaded once; never changes)
  float trc[52];
  #pragma unroll
  for (int j = 0; j < 52; ++j) trc[j] = trans[j * 52 + kk];
  __syncthreads();

  float part = trans[50 * 52 + kk] + flds[kk];   // START row = 50
  if (lane < 52) pl[lane] = part;

  for (int t = 1; t < 200; ++t) {
    const float ftk = flds[t * 52 + kk];
    float pa[52];
    #pragma unroll
    for (int q = 0; q < 13; ++q) {
      float4 v = *(const float4*)&pl[q * 4];     // broadcast read
      pa[q * 4 + 0] = v.x; pa[q * 4 + 1] = v.y;
      pa[q * 4 + 2] = v.z; pa[q * 4 + 3] = v.w;
    }
    float mv0 = -1e30f, mv1 = -1e30f, mv2 = -1e30f, mv3 = -1e30f;
    int mj0 = 0, mj1 = 13, mj2 = 26, mj3 = 39;
    #pragma unroll
    for (int q = 0; q < 13; ++q) {
      float c0v = (pa[q] + trc[q]) + ftk;               // np eval order
      if (c0v > mv0) { mv0 = c0v; mj0 = q; }
      float c1v = (pa[13 + q] + trc[13 + q]) + ftk;
      if (c1v > mv1) { mv1 = c1v; mj1 = 13 + q; }
      float c2v = (pa[26 + q] + trc[26 + q]) + ftk;
      if (c2v > mv2) { mv2 = c2v; mj2 = 26 + q; }
      float c3v = (pa[39 + q] + trc[39 + q]) + ftk;
      if (c3v > mv3) { mv3 = c3v; mj3 = 39 + q; }
    }
    float mv = mv0; int mj = mj0;                        // ordered combine:
    if (mv1 > mv) { mv = mv1; mj = mj1; }                // first-index ties
    if (mv2 > mv) { mv = mv2; mj = mj2; }
    if (mv3 > mv) { mv = mv3; mj = mj3; }
    const bool m = t < len;
    if (lane < 52) {
      bp[(t - 1) * 52 + lane] = (unsigned char)(m ? mj : lane);
      if (m) { part = mv; pl[lane] = mv; }
    }
  }

  float fin = (lane < 52) ? (part + trans[lane * 52 + 51]) : -1e30f;  // STOP=51
  int bi = lane;
  #pragma unroll
  for (int off = 32; off; off >>= 1) {
    float ov = __shfl_down(fin, off);
    int oi = __shfl_down(bi, off);
    if (ov > fin || (ov == fin && oi < bi)) { fin = ov; bi = oi; }
  }
  if (lane == 0) {
    out[b] = fin;
    int tag = bi;
    float* dec = out + 256 + (size_t)b * 200;
    dec[199] = (199 < len) ? (float)tag : 0.f;
    for (int i = 198; i >= 0; --i) {
      tag = bp[i * 52 + tag];
      dec[i] = (i < len) ? (float)tag : 0.f;
    }
  }
}

extern "C" void kernel_launch(void* const* d_in, const int* in_sizes, int n_in,
                              void* d_out, int out_size, void* d_ws, size_t ws_size,
                              hipStream_t stream) {
  const int*   bin  = (const int*)d_in[0];
  const int*   bfe  = (const int*)d_in[1];
  const int*   blen = (const int*)d_in[2];
  const float* ctab = (const float*)d_in[5];
  const float* ftab = (const float*)d_in[6];
  const float* wihf = (const float*)d_in[7];
  const float* whhf = (const float*)d_in[8];
  const float* bf   = (const float*)d_in[9];
  const float* wihb = (const float*)d_in[10];
  const float* whhb = (const float*)d_in[11];
  const float* bb   = (const float*)d_in[12];
  const float* wtag = (const float*)d_in[13];
  const float* btag = (const float*)d_in[14];
  const float* trn  = (const float*)d_in[15];

  (void)hipFuncSetAttribute(reinterpret_cast<const void*>(lstm_chunk),
                            hipFuncAttributeMaxDynamicSharedMemorySize,
                            SMEM_BYTES);

  const size_t FIXED_F = 29271040;
  size_t ws_f = ws_size / sizeof(float);
  int C = 1;
  const int cands[8] = {25, 20, 10, 8, 5, 4, 2, 1};
  for (int u = 0; u < 8; ++u) {
    if (FIXED_F + (size_t)2 * cands[u] * 262144 <= ws_f) { C = cands[u]; break; }
  }

  float* ws  = (float*)d_ws;
  float* xgf = ws;
  float* xgb = xgf + (size_t)C * 262144;
  float* hst = xgb + (size_t)C * 262144;    // 2 slots x 2 dir x 256 x 256
  float* cst = hst + 262144;
  float* hout = cst + 131072;               // 2 dir x 200 x 256 x 256
  float* fts  = hout + 26214400;
  unsigned* bar = (unsigned*)(fts + 2662400); // 32 groups x 16 js flags
  float* out  = (float*)d_out;

  hipMemsetAsync(hst, 0, (size_t)(262144 + 131072) * sizeof(float), stream);
  hipMemsetAsync(bar, 0, 1024 * sizeof(unsigned), stream);

  const int nchunks = 200 / C;
  for (int c = 0; c < nchunks; ++c) {
    xg_gemm<<<dim3(4 * C, 8), 256, 0, stream>>>(bin, bfe, blen, ctab, ftab,
                                                wihf, bf, xgf, c * C, 1);
    xg_gemm<<<dim3(4 * C, 8), 256, 0, stream>>>(bin, bfe, blen, ctab, ftab,
                                                wihb, bb, xgb, 199 - c * C, -1);
    lstm_chunk<<<dim3(16, 8, 2), 512, SMEM_BYTES, stream>>>(
        xgf, xgb, whhf, whhb, blen, hst, cst, hout, bar, c * C, C);
  }
  feats_kernel<<<dim3(200, 8), 256, 0, stream>>>(hout, wtag, btag, fts);
  viterbi_kernel<<<256, 64, 0, stream>>>(fts, trn, blen, out);
}

// Round 8
// 2536.118 us; speedup vs baseline: 2.1807x; 2.1807x over previous
//
#include <hip/hip_runtime.h>
#include <math.h>

#define T_ 200
#define WROW 284                       // LDS row stride (256 + swizzle room)
#define SMEM_FLOATS (128 * WROW + 16 * WROW)
#define SMEM_BYTES (SMEM_FLOATS * 4)   // 163,584 <= 163,840 (160 KiB)

__device__ __forceinline__ float fsig(float x) {
  return 1.f / (1.f + __expf(-x));
}
__device__ __forceinline__ float ftanh(float x) {
  return 1.f - 2.f / (__expf(2.f * x) + 1.f);   // exact at +-inf, no NaN
}

// ---------------- xg GEMM v2: 128x128 tile, 8x8 micro, fused embedding gather,
// masked-tile early exit. C[rows x 1024] = emb[rows x 256] @ Wih^T + bias.
// A staged transposed with col swizzle m+((m>>5)<<2) -> 2-way (free) reads.
__global__ __launch_bounds__(256) void xg_gemm(
    const int* __restrict__ bin, const int* __restrict__ bfe,
    const int* __restrict__ blen,
    const float* __restrict__ ctab, const float* __restrict__ ftab,
    const float* __restrict__ wih, const float* __restrict__ bias,
    float* __restrict__ xgslot, int t0, int sgn) {
  const int m0 = blockIdx.x * 128;
  const int rloc = m0 >> 8;
  const int t_blk = t0 + sgn * rloc;
  if (t_blk >= blen[m0 & 255]) return;   // fully masked tile (sorted lengths)

  __shared__ float As[32][140];   // [k][m swizzled]
  __shared__ float Bs[32][132];   // [k][n]
  const int tid = threadIdx.x;
  const int n0 = blockIdx.y * 128;
  const int mm = tid & 15;
  const int nn = tid >> 4;

  const int ra = tid & 127;            // staging row (A: m, B: n)
  const int ka = (tid >> 7) << 4;      // k-offset 0 or 16

  const int bcol = (m0 + ra) & 255;
  const float* cr = ctab + ((size_t)bin[bcol * T_ + t_blk] << 8);
  const float* fr = ftab + ((size_t)bfe[bcol * T_ + t_blk] << 8);
  const float* br = wih + (size_t)(n0 + ra) * 256;
  const int cwa = ra + ((ra >> 5) << 2);   // swizzled A col for m=ra

  float acc[8][8];
  #pragma unroll
  for (int i = 0; i < 8; ++i)
    #pragma unroll
    for (int j = 0; j < 8; ++j) acc[i][j] = 0.f;

  const int am0 = mm * 8 + ((mm >> 2) << 2);   // swizzled base col for A reads
  const int bn0 = nn * 8;

  for (int ks = 0; ks < 256; ks += 32) {
    float4 c4[4], f4v[4], b4[4];
    #pragma unroll
    for (int w = 0; w < 4; ++w) {
      c4[w]  = *(const float4*)(cr + ks + ka + w * 4);
      f4v[w] = *(const float4*)(fr + ks + ka + w * 4);
      b4[w]  = *(const float4*)(br + ks + ka + w * 4);
    }
    __syncthreads();   // previous iteration's consumers done
    #pragma unroll
    for (int w = 0; w < 4; ++w) {
      int kk = ka + w * 4;
      As[kk + 0][cwa] = c4[w].x * f4v[w].x;
      As[kk + 1][cwa] = c4[w].y * f4v[w].y;
      As[kk + 2][cwa] = c4[w].z * f4v[w].z;
      As[kk + 3][cwa] = c4[w].w * f4v[w].w;
      Bs[kk + 0][ra] = b4[w].x;
      Bs[kk + 1][ra] = b4[w].y;
      Bs[kk + 2][ra] = b4[w].z;
      Bs[kk + 3][ra] = b4[w].w;
    }
    __syncthreads();
    #pragma unroll 4
    for (int k = 0; k < 32; ++k) {
      float4 a0 = *(const float4*)&As[k][am0];
      float4 a1 = *(const float4*)&As[k][am0 + 4];
      float4 b0 = *(const float4*)&Bs[k][bn0];
      float4 b1 = *(const float4*)&Bs[k][bn0 + 4];
      float am[8] = {a0.x, a0.y, a0.z, a0.w, a1.x, a1.y, a1.z, a1.w};
      float bn[8] = {b0.x, b0.y, b0.z, b0.w, b1.x, b1.y, b1.z, b1.w};
      #pragma unroll
      for (int i = 0; i < 8; ++i)
        #pragma unroll
        for (int j = 0; j < 8; ++j)
          acc[i][j] += am[i] * bn[j];
    }
  }

  float4 bv0 = *(const float4*)(bias + n0 + bn0);
  float4 bv1 = *(const float4*)(bias + n0 + bn0 + 4);
  #pragma unroll
  for (int i = 0; i < 8; ++i) {
    int row = m0 + mm * 8 + i;
    float4 o0, o1;
    o0.x = acc[i][0] + bv0.x; o0.y = acc[i][1] + bv0.y;
    o0.z = acc[i][2] + bv0.z; o0.w = acc[i][3] + bv0.w;
    o1.x = acc[i][4] + bv1.x; o1.y = acc[i][5] + bv1.y;
    o1.z = acc[i][6] + bv1.z; o1.w = acc[i][7] + bv1.w;
    *(float4*)(xgslot + (size_t)row * 1024 + n0 + bn0) = o0;
    *(float4*)(xgslot + (size_t)row * 1024 + n0 + bn0 + 4) = o1;
  }
}

// ---------------- persistent LSTM chunk: r6-proven v4 (ks8/bg4/rg16, W in LDS,
// fetch_add barrier) with ONE change: h staging via dwordx4 agent-scope (sc1
// ONLY — sc0+sc1=system scope caused r7's HBM writeback storm).
__global__ __launch_bounds__(512, 1) void lstm_chunk(
    const float* __restrict__ xgf, const float* __restrict__ xgb,
    const float* __restrict__ whf, const float* __restrict__ whb,
    const int* __restrict__ blen,
    float* __restrict__ hst, float* __restrict__ cst,
    float* __restrict__ hout, unsigned* __restrict__ bar,
    int s0, int nsteps) {
  extern __shared__ float smem[];
  float* wlds = smem;                 // [128][WROW]
  float* hlds = smem + 128 * WROW;    // [16][WROW]

  const int bc = blockIdx.x, js = blockIdx.y, dir = blockIdx.z;
  const int tid = threadIdx.x;
  const int ks = tid & 7;
  const int bg = (tid >> 3) & 3;
  const int rg = tid >> 5;            // 0..15
  const int grp = dir * 16 + bc;
  const float* wh = dir ? whb : whf;
  const float* xgp = dir ? xgb : xgf;

  // ---- stage W once per chunk (permuted rows: prow = rgs*8 + g*2 + u)
  #pragma unroll
  for (int i = 0; i < 16; ++i) {
    int f = tid + i * 512;            // float4 id 0..8191
    int prow = f >> 6;
    int k = (f & 63) << 2;
    int g = (prow >> 1) & 3, u = prow & 1, rgs = prow >> 3;
    int jg = js * 32 + rgs * 2 + u;
    float4 v = *(const float4*)(wh + ((size_t)(g * 256 + jg)) * 256 + k);
    *(float4*)&wlds[prow * WROW + k + ((k >> 5) << 2)] = v;
  }

  const int bl_th = bg * 4 + (ks & 3);      // local batch 0..15
  const int b_th = bc * 16 + bl_th;         // global batch
  const int u_th = ks >> 2;
  const int jth = js * 32 + rg * 2 + u_th;  // this thread's j
  const int cjth = jth + ((jth >> 5) << 2); // swizzled col of jth
  const int len_th = blen[b_th];
  float c0 = cst[((size_t)dir * 256 + b_th) * 256 + jth];

  __syncthreads();   // W staged

  for (int r = 0; r < nsteps; ++r) {
    const int s = s0 + r;
    const int tt = dir ? (199 - s) : s;
    const int rslot = s & 1, wslot = 1 - rslot;

    // ---- xq loads first (latency hidden under staging + GEMM)
    float xq[4];
    #pragma unroll
    for (int g = 0; g < 4; ++g)
      xq[g] = xgp[((size_t)r * 256 + b_th) * 1024 + g * 256 + jth];

    // ---- stage h[16 b][256 k]: 2 agent-scope (sc1) dwordx4 per thread
    const float* hsrc = hst + (((size_t)(rslot * 2 + dir)) * 256 + bc * 16) * 256;
    {
      const int f0 = tid, f1 = tid + 512;        // float4 ids
      const int b0i = f0 >> 6, k0 = (f0 & 63) << 2;
      const int b1i = f1 >> 6, k1 = (f1 & 63) << 2;
      const float* p0 = hsrc + (b0i << 8) + k0;
      const float* p1 = hsrc + (b1i << 8) + k1;
      float4 v0, v1;
      asm volatile(
          "global_load_dwordx4 %0, %2, off sc1\n\t"
          "global_load_dwordx4 %1, %3, off sc1\n\t"
          "s_waitcnt vmcnt(0)"
          : "=&v"(v0), "=&v"(v1)
          : "v"(p0), "v"(p1)
          : "memory");
      *(float4*)&hlds[b0i * WROW + k0 + ((k0 >> 5) << 2)] = v0;
      *(float4*)&hlds[b1i * WROW + k1 + ((k1 >> 5) << 2)] = v1;
    }
    __syncthreads();

    // ---- GEMM: acc[i][bb], i = gate-pair row, bb = batch within quad
    float acc[8][4];
    #pragma unroll
    for (int i = 0; i < 8; ++i)
      #pragma unroll
      for (int bb = 0; bb < 4; ++bb) acc[i][bb] = 0.f;

    #pragma unroll
    for (int kq = 0; kq < 8; ++kq) {
      const int col = ks * 36 + kq * 4;
      float4 h4[4];
      #pragma unroll
      for (int bb = 0; bb < 4; ++bb)
        h4[bb] = *(const float4*)&hlds[(bg * 4 + bb) * WROW + col];
      #pragma unroll
      for (int i = 0; i < 8; ++i) {
        float4 w4 = *(const float4*)&wlds[(rg * 8 + i) * WROW + col];
        #pragma unroll
        for (int bb = 0; bb < 4; ++bb)
          acc[i][bb] += w4.x * h4[bb].x + w4.y * h4[bb].y +
                        w4.z * h4[bb].z + w4.w * h4[bb].w;
      }
    }

    // ---- butterfly over ks: xor1/xor2 route batches, xor4 finishes k-reduce
    const int bit0 = ks & 1, bit1 = (ks >> 1) & 1;
    float fin[8];
    #pragma unroll
    for (int i = 0; i < 8; ++i) {
      float k0 = bit0 ? acc[i][1] : acc[i][0];
      float s0v = bit0 ? acc[i][0] : acc[i][1];
      float k1 = bit0 ? acc[i][3] : acc[i][2];
      float s1v = bit0 ? acc[i][2] : acc[i][3];
      float r0 = k0 + __shfl_xor(s0v, 1);
      float r1 = k1 + __shfl_xor(s1v, 1);
      float k2 = bit1 ? r1 : r0;
      float s2v = bit1 ? r0 : r1;
      float r2 = k2 + __shfl_xor(s2v, 2);
      fin[i] = r2 + __shfl_xor(r2, 4);
    }

    // ---- cell update (1 cell per thread: batch b_th, hidden jth)
    float gi = fsig((u_th ? fin[1] : fin[0]) + xq[0]);
    float gf = fsig((u_th ? fin[3] : fin[2]) + xq[1]);
    float gg = ftanh((u_th ? fin[5] : fin[4]) + xq[2]);
    float go = fsig((u_th ? fin[7] : fin[6]) + xq[3]);
    float cn = gf * c0 + gi * gg;
    float hn = go * ftanh(cn);
    const bool mk = tt < len_th;
    if (mk) c0 = cn;
    float hold = hlds[bl_th * WROW + cjth];
    float hsv = mk ? hn : hold;
    __hip_atomic_store(
        hst + (((size_t)(wslot * 2 + dir)) * 256 + b_th) * 256 + jth,
        hsv, __ATOMIC_RELAXED, __HIP_MEMORY_SCOPE_AGENT);

    // ---- drain h stores, signal, hout store overlaps the poll
    asm volatile("s_waitcnt vmcnt(0)" ::: "memory");
    __syncthreads();
    if (tid == 0)
      __hip_atomic_fetch_add(&bar[grp * 32], 1u, __ATOMIC_RELAXED,
                             __HIP_MEMORY_SCOPE_AGENT);
    hout[(((size_t)dir * 200 + tt) * 256 + b_th) * 256 + jth] = mk ? hn : 0.f;
    if (tid == 0) {
      const unsigned tgt = 8u * (unsigned)(s + 1);
      while (__hip_atomic_load(&bar[grp * 32], __ATOMIC_RELAXED,
                               __HIP_MEMORY_SCOPE_AGENT) < tgt) {}
    }
    __syncthreads();
  }

  cst[((size_t)dir * 256 + b_th) * 256 + jth] = c0;
}

// ---------------- feats[b][t][k] = [hf|hb] . W_tag[k] + b_tag[k]  (r2, proven)
__global__ __launch_bounds__(256) void feats_kernel(
    const float* __restrict__ h_out, const float* __restrict__ wtag,
    const float* __restrict__ btag, float* __restrict__ feats) {
  __shared__ float hcat[32][512];
  const int t = blockIdx.x, bc = blockIdx.y;
  const int tid = threadIdx.x;
  const float* hf = h_out + (((size_t)0 * 200 + t) * 256 + bc * 32) * 256;
  const float* hb = h_out + (((size_t)1 * 200 + t) * 256 + bc * 32) * 256;
  for (int i = tid; i < 2048; i += 256) {
    int row = i >> 6, c4 = (i & 63) << 2;
    *(float4*)&hcat[row][c4] = *(const float4*)(hf + (size_t)row * 256 + c4);
    *(float4*)&hcat[row][256 + c4] = *(const float4*)(hb + (size_t)row * 256 + c4);
  }
  __syncthreads();
  const int kk = tid & 63;
  const int bg = tid >> 6;
  if (kk < 52) {
    float acc[8];
    #pragma unroll
    for (int i = 0; i < 8; ++i) acc[i] = 0.f;
    const float* wr = wtag + (size_t)kk * 512;
    for (int jq = 0; jq < 128; ++jq) {
      float4 wv = *(const float4*)(wr + jq * 4);
      #pragma unroll
      for (int bi = 0; bi < 8; ++bi) {
        float4 hv = *(const float4*)&hcat[bg * 8 + bi][jq * 4];
        acc[bi] += wv.x * hv.x + wv.y * hv.y + wv.z * hv.z + wv.w * hv.w;
      }
    }
    float bv = btag[kk];
    #pragma unroll
    for (int bi = 0; bi < 8; ++bi)
      feats[(size_t)(bc * 32 + bg * 8 + bi) * 10400 + t * 52 + kk] = acc[bi] + bv;
  }
}

// ---------------- Viterbi v3 (r7, passed): one WAVE per batch row.
__global__ __launch_bounds__(64) void viterbi_kernel(
    const float* __restrict__ feats, const float* __restrict__ trans,
    const int* __restrict__ blen, float* __restrict__ out) {
  __shared__ float flds[10400];
  __shared__ float pl[56];
  __shared__ unsigned char bp[199 * 52];

  const int b = blockIdx.x;
  const int lane = threadIdx.x;
  const int kk = (lane < 52) ? lane : 0;
  const float* fb = feats + (size_t)b * 10400;
  const int len = blen[b];

  for (int i = lane; i < 2600; i += 64)
    *(float4*)&flds[i * 4] = *(const float4*)(fb + i * 4);

  float trc[52];
  #pragma unroll
  for (int j = 0; j < 52; ++j) trc[j] = trans[j * 52 + kk];
  __syncthreads();

  float part = trans[50 * 52 + kk] + flds[kk];   // START row = 50
  if (lane < 52) pl[lane] = part;

  for (int t = 1; t < 200; ++t) {
    const float ftk = flds[t * 52 + kk];
    float pa[52];
    #pragma unroll
    for (int q = 0; q < 13; ++q) {
      float4 v = *(const float4*)&pl[q * 4];
      pa[q * 4 + 0] = v.x; pa[q * 4 + 1] = v.y;
      pa[q * 4 + 2] = v.z; pa[q * 4 + 3] = v.w;
    }
    float mv0 = -1e30f, mv1 = -1e30f, mv2 = -1e30f, mv3 = -1e30f;
    int mj0 = 0, mj1 = 13, mj2 = 26, mj3 = 39;
    #pragma unroll
    for (int q = 0; q < 13; ++q) {
      float c0v = (pa[q] + trc[q]) + ftk;
      if (c0v > mv0) { mv0 = c0v; mj0 = q; }
      float c1v = (pa[13 + q] + trc[13 + q]) + ftk;
      if (c1v > mv1) { mv1 = c1v; mj1 = 13 + q; }
      float c2v = (pa[26 + q] + trc[26 + q]) + ftk;
      if (c2v > mv2) { mv2 = c2v; mj2 = 26 + q; }
      float c3v = (pa[39 + q] + trc[39 + q]) + ftk;
      if (c3v > mv3) { mv3 = c3v; mj3 = 39 + q; }
    }
    float mv = mv0; int mj = mj0;
    if (mv1 > mv) { mv = mv1; mj = mj1; }
    if (mv2 > mv) { mv = mv2; mj = mj2; }
    if (mv3 > mv) { mv = mv3; mj = mj3; }
    const bool m = t < len;
    if (lane < 52) {
      bp[(t - 1) * 52 + lane] = (unsigned char)(m ? mj : lane);
      if (m) { part = mv; pl[lane] = mv; }
    }
  }

  float fin = (lane < 52) ? (part + trans[lane * 52 + 51]) : -1e30f;
  int bi = lane;
  #pragma unroll
  for (int off = 32; off; off >>= 1) {
    float ov = __shfl_down(fin, off);
    int oi = __shfl_down(bi, off);
    if (ov > fin || (ov == fin && oi < bi)) { fin = ov; bi = oi; }
  }
  if (lane == 0) {
    out[b] = fin;
    int tag = bi;
    float* dec = out + 256 + (size_t)b * 200;
    dec[199] = (199 < len) ? (float)tag : 0.f;
    for (int i = 198; i >= 0; --i) {
      tag = bp[i * 52 + tag];
      dec[i] = (i < len) ? (float)tag : 0.f;
    }
  }
}

extern "C" void kernel_launch(void* const* d_in, const int* in_sizes, int n_in,
                              void* d_out, int out_size, void* d_ws, size_t ws_size,
                              hipStream_t stream) {
  const int*   bin  = (const int*)d_in[0];
  const int*   bfe  = (const int*)d_in[1];
  const int*   blen = (const int*)d_in[2];
  const float* ctab = (const float*)d_in[5];
  const float* ftab = (const float*)d_in[6];
  const float* wihf = (const float*)d_in[7];
  const float* whhf = (const float*)d_in[8];
  const float* bf   = (const float*)d_in[9];
  const float* wihb = (const float*)d_in[10];
  const float* whhb = (const float*)d_in[11];
  const float* bb   = (const float*)d_in[12];
  const float* wtag = (const float*)d_in[13];
  const float* btag = (const float*)d_in[14];
  const float* trn  = (const float*)d_in[15];

  (void)hipFuncSetAttribute(reinterpret_cast<const void*>(lstm_chunk),
                            hipFuncAttributeMaxDynamicSharedMemorySize,
                            SMEM_BYTES);

  const size_t FIXED_F = 29271040;
  size_t ws_f = ws_size / sizeof(float);
  int C = 1;
  const int cands[10] = {50, 40, 25, 20, 10, 8, 5, 4, 2, 1};
  for (int u = 0; u < 10; ++u) {
    if (FIXED_F + (size_t)2 * cands[u] * 262144 <= ws_f) { C = cands[u]; break; }
  }

  float* ws  = (float*)d_ws;
  float* xgf = ws;
  float* xgb = xgf + (size_t)C * 262144;
  float* hst = xgb + (size_t)C * 262144;    // 2 slots x 2 dir x 256 x 256
  float* cst = hst + 262144;
  float* hout = cst + 131072;               // 2 dir x 200 x 256 x 256
  float* fts  = hout + 26214400;
  unsigned* bar = (unsigned*)(fts + 2662400); // 32 groups x stride 32
  float* out  = (float*)d_out;

  hipMemsetAsync(hst, 0, (size_t)(262144 + 131072) * sizeof(float), stream);
  hipMemsetAsync(bar, 0, 1024 * sizeof(unsigned), stream);

  const int nchunks = 200 / C;
  for (int c = 0; c < nchunks; ++c) {
    xg_gemm<<<dim3(2 * C, 8), 256, 0, stream>>>(bin, bfe, blen, ctab, ftab,
                                                wihf, bf, xgf, c * C, 1);
    xg_gemm<<<dim3(2 * C, 8), 256, 0, stream>>>(bin, bfe, blen, ctab, ftab,
                                                wihb, bb, xgb, 199 - c * C, -1);
    lstm_chunk<<<dim3(16, 8, 2), 512, SMEM_BYTES, stream>>>(
        xgf, xgb, whhf, whhb, blen, hst, cst, hout, bar, c * C, C);
  }
  feats_kernel<<<dim3(200, 8), 256, 0, stream>>>(hout, wtag, btag, fts);
  viterbi_kernel<<<256, 64, 0, stream>>>(fts, trn, blen, out);
}